// Round 8
// baseline (857.437 us; speedup 1.0000x reference)
//
#include <hip/hip_runtime.h>

#define F 128
#define NNODE 2000
#define NEDGE 64000
#define NBATCH 4
#define NN 8000          // NBATCH*NNODE
#define NRELC 18
#define KTOP 800         // int(0.1*8000)
#define AVGLOG 3.4965075614664802f   // float(np.log(33.0))
#define EPSSTD 1e-5f
#define NCHUNK 250       // NEDGE/256

// ---------------- setup kernels ----------------

__global__ void k_init(float* __restrict__ cur, int* __restrict__ hist){
  int i = blockIdx.x*blockDim.x + threadIdx.x;
  int stride = gridDim.x*blockDim.x;
  for(int t=i;t<NN*F;t+=stride) cur[t]=0.f;
  for(int t=i;t<NCHUNK*NNODE;t+=stride) hist[t]=0;
}

// single block: indices, rel_emb, Rb = rel@Wl[128:], initial scores, sel0, xr scatter
__global__ void k_meta(const int* __restrict__ h_index, const int* __restrict__ r_index,
                       const int* __restrict__ t_index, const float* __restrict__ hidden,
                       const float* __restrict__ rel_hidden, const float* __restrict__ rel_table,
                       const float* __restrict__ Wl, const float* __restrict__ bl,
                       const float* __restrict__ W1, const float* __restrict__ b1,
                       const float* __restrict__ W2, const float* __restrict__ b2,
                       float* __restrict__ cur, unsigned char* __restrict__ sel,
                       int* __restrict__ meta_i, float* __restrict__ meta_f){
  __shared__ int sh_ist[NBATCH], sh_h0[NBATCH], sh_t0[NBATCH], sh_r0[NBATCH];
  __shared__ float sh_rel[NBATCH*F];
  __shared__ float sh_z[F], sh_zz[F];
  __shared__ float sh_sc[NBATCH];
  __shared__ int sh_excl;
  int tid = threadIdx.x;
  if(tid<NBATCH){
    int b=tid;
    int h00=h_index[b*32];
    int ist=1;
    for(int j=1;j<32;j++) if(h_index[b*32+j]!=h00) ist=0;
    sh_ist[b]=ist;
    sh_h0[b] = (ist ? h_index[b*32] : t_index[b*32]) + b*NNODE;
    sh_t0[b] = (ist ? t_index[b*32] : h_index[b*32]) + b*NNODE;
    sh_r0[b] = r_index[b*32] + (ist?0:NRELC);
  }
  __syncthreads();
  if(tid<NBATCH*32){
    int b=tid>>5;
    meta_i[16+tid] = (sh_ist[b] ? t_index[tid] : h_index[tid]) + b*NNODE; // final gather idx
  }
  for(int t=tid;t<NBATCH*F;t+=blockDim.x){
    int b=t>>7, f=t&127;
    float v = rel_table[sh_r0[b]*F+f];
    sh_rel[t]=v; meta_f[t]=v;
  }
  __syncthreads();
  // Rb[b][f] = sum_k rel[b][k]*Wl[128+k][f]
  for(int t=tid;t<NBATCH*F;t+=blockDim.x){
    int b=t>>7, f=t&127;
    float acc=0.f;
    for(int k=0;k<F;k++) acc += sh_rel[b*F+k]*Wl[(F+k)*F+f];
    meta_f[512+t]=acc;
  }
  __syncthreads();
  // initial scores sc[b] = _score(hidden_b, rel_b)
  for(int b=0;b<NBATCH;b++){
    if(tid<F){
      float acc=0.f;
      for(int k=0;k<F;k++) acc += hidden[b*F+k]*Wl[k*F+tid];
      float heur = acc + meta_f[512+b*F+tid] + bl[tid];
      sh_z[tid] = heur*hidden[b*F+tid];
    }
    __syncthreads();
    if(tid<F){
      float acc=0.f;
      for(int k=0;k<F;k++) acc += sh_z[k]*W1[k*F+tid];
      acc += b1[tid];
      sh_zz[tid] = acc>0.f?acc:0.f;
    }
    __syncthreads();
    if(tid==0){
      float s=0.f;
      for(int k=0;k<F;k++) s += sh_zz[k]*W2[k];
      sh_sc[b] = s + b2[0];
      meta_f[1024+b]=sh_sc[b];
    }
    __syncthreads();
  }
  if(tid==0){
    // layer-0 top_k over repeat(s0,N): only first-8000 entries matter; all zero-ties
    // get selected. Exclusion only if batch0's h0 node < 4 AND its score negative.
    sh_excl = (sh_h0[0]<4 && sh_sc[0]<0.f) ? sh_h0[0] : -1;
    meta_i[8]=sh_excl;
  }
  __syncthreads();
  int ex = sh_excl;
  for(int t=tid;t<NN;t+=blockDim.x)
    sel[t] = (ex>=0 && (t/NNODE)==ex) ? 0 : 1;
  // xr scatter: t rows first, then h rows (h wins collisions)
  for(int t=tid;t<NBATCH*F;t+=blockDim.x){
    int b=t>>7, f=t&127;
    cur[sh_t0[b]*F+f] = rel_hidden[t];
  }
  __syncthreads();
  for(int t=tid;t<NBATCH*F;t+=blockDim.x){
    int b=t>>7, f=t&127;
    cur[sh_h0[b]*F+f] = hidden[t];
  }
}

// stable counting-sort CSR build, O(E)
__global__ __launch_bounds__(256) void k_hist(const int* __restrict__ edge,
                                              int* __restrict__ hist, int* __restrict__ rank){
  __shared__ int dsts[256];
  int chunk = blockIdx.x;
  int tid = threadIdx.x;
  int e = chunk*256 + tid;
  int d = edge[NEDGE + e];
  dsts[tid] = d;
  __syncthreads();
  int before=0, after=0;
  #pragma unroll 8
  for(int t=0;t<256;t++){
    int dt = dsts[t];
    before += (dt==d) & (t<tid);
    after  += (dt==d) & (t>tid);
  }
  rank[e] = before;
  if(after==0) hist[chunk*NNODE + d] = before+1;
}

__global__ void k_chunkscan(int* __restrict__ hist, int* __restrict__ deg){
  int node = blockIdx.x*blockDim.x + threadIdx.x;
  if(node>=NNODE) return;
  int run=0;
  for(int c=0;c<NCHUNK;c++){
    int v = hist[c*NNODE+node];
    hist[c*NNODE+node] = run;
    run += v;
  }
  deg[node]=run;
}

__global__ void k_scan(const int* __restrict__ deg, int* __restrict__ csr_start){
  __shared__ int a[2048], b[2048];
  int tid=threadIdx.x;
  for(int i=tid;i<2048;i+=256) a[i] = (i<NNODE)? deg[i] : 0;
  __syncthreads();
  int* src=a; int* dst=b;
  for(int off=1; off<2048; off<<=1){
    for(int i=tid;i<2048;i+=256){
      int v = src[i];
      if(i>=off) v += src[i-off];
      dst[i]=v;
    }
    __syncthreads();
    int* t=src; src=dst; dst=t;
  }
  for(int i=tid;i<=NNODE;i+=256) csr_start[i] = (i==0)?0:src[i-1];
}

__global__ void k_scatter(const int* __restrict__ edge, const int* __restrict__ hist,
                          const int* __restrict__ rank, const int* __restrict__ csr_start,
                          int* __restrict__ csr_src){
  int e = blockIdx.x*blockDim.x + threadIdx.x;
  if(e<NEDGE){
    int d = edge[NEDGE+e];
    int pos = csr_start[d] + hist[(e>>8)*NNODE + d] + rank[e];
    csr_src[pos] = edge[e];
  }
}

// ---------------- per-layer kernels ----------------

// exact top-800-of-8000 with lax.top_k tie semantics (lower index wins ties)
__global__ void k_sel(const float* __restrict__ score, unsigned char* __restrict__ sel){
  __shared__ float s[NN];
  int tid=threadIdx.x;
  float4* s4 = (float4*)s;
  const float4* g4 = (const float4*)score;
  for(int i=tid;i<NN/4;i+=256) s4[i]=g4[i];
  __syncthreads();
  int node = blockIdx.x*32 + (tid>>3);
  int part = tid & 7;
  float si = s[node];
  int rank = 0;
  for(int q=part*(NN/32); q<(part+1)*(NN/32); q++){
    float4 v = s4[q];
    int j = q*4;
    rank += (v.x>si)||(v.x==si && j  <node);
    rank += (v.y>si)||(v.y==si && j+1<node);
    rank += (v.z>si)||(v.z==si && j+2<node);
    rank += (v.w>si)||(v.w==si && j+3<node);
  }
  for(int o=4;o;o>>=1) rank += __shfl_down(rank, o, 8);
  if(part==0) sel[node] = (rank < KTOP) ? 1 : 0;
}

// fp32 GEMM, NO LDS: operands stream global->L1/L2->registers.
// BM=16, BN=128, 256 threads, 2x4 thread tile; grid 500 blocks = 2 blocks/CU
// (2 waves/SIMD for latency hiding). Depth-4 register prefetch (named buffers,
// static indexing): loads issued 4 k-blocks (~256 issue-cycles) before use.
// Per-output-element k-sequential FMA chain (bitwise-stable vs reference).
// MODE 0: AB = cur @ [Wpre_dst|Wpre_src] (+bpre on first 128 cols), out ld 256
// MODE 1: H  = [cur|AGG|AGG*f1|AGG*f2] @ Wpost + bpost   (virtual A)

#define RELOAD2(AA,BB,tt){ int kq=(tt)*4; \
  AA[0]=*(const float4*)(Ab0 + kq); \
  AA[1]=*(const float4*)(Ab0 + (size_t)lda + kq); \
  BB[0]=*(const float4*)(Wseg + (size_t)(kq  )*F); \
  BB[1]=*(const float4*)(Wseg + (size_t)(kq+1)*F); \
  BB[2]=*(const float4*)(Wseg + (size_t)(kq+2)*F); \
  BB[3]=*(const float4*)(Wseg + (size_t)(kq+3)*F); }

#define CONSUME2(AA,BB,tnext){ \
  float4 a0=AA[0],a1=AA[1]; \
  float4 b0=BB[0],b1=BB[1],b2=BB[2],b3=BB[3]; \
  if((tnext)<nt) RELOAD2(AA,BB,tnext); \
  if(dm){ a0.x*=m0;a0.y*=m0;a0.z*=m0;a0.w*=m0; a1.x*=m1;a1.y*=m1;a1.z*=m1;a1.w*=m1; } \
  acc[0][0]+=a0.x*b0.x; acc[0][1]+=a0.x*b0.y; acc[0][2]+=a0.x*b0.z; acc[0][3]+=a0.x*b0.w; \
  acc[1][0]+=a1.x*b0.x; acc[1][1]+=a1.x*b0.y; acc[1][2]+=a1.x*b0.z; acc[1][3]+=a1.x*b0.w; \
  acc[0][0]+=a0.y*b1.x; acc[0][1]+=a0.y*b1.y; acc[0][2]+=a0.y*b1.z; acc[0][3]+=a0.y*b1.w; \
  acc[1][0]+=a1.y*b1.x; acc[1][1]+=a1.y*b1.y; acc[1][2]+=a1.y*b1.z; acc[1][3]+=a1.y*b1.w; \
  acc[0][0]+=a0.z*b2.x; acc[0][1]+=a0.z*b2.y; acc[0][2]+=a0.z*b2.z; acc[0][3]+=a0.z*b2.w; \
  acc[1][0]+=a1.z*b2.x; acc[1][1]+=a1.z*b2.y; acc[1][2]+=a1.z*b2.z; acc[1][3]+=a1.z*b2.w; \
  acc[0][0]+=a0.w*b3.x; acc[0][1]+=a0.w*b3.y; acc[0][2]+=a0.w*b3.z; acc[0][3]+=a0.w*b3.w; \
  acc[1][0]+=a1.w*b3.x; acc[1][1]+=a1.w*b3.y; acc[1][2]+=a1.w*b3.z; acc[1][3]+=a1.w*b3.w; }

template<int MODE>
__global__ __launch_bounds__(256) void k_gemm(
    const float* __restrict__ A, const float* __restrict__ W,
    const float* __restrict__ bias, float* __restrict__ out,
    const float* __restrict__ AGGp, const float* __restrict__ F1p,
    const float* __restrict__ F2p, const float* __restrict__ CURp, int Ktot)
{
  int tid = threadIdx.x;
  int r0 = blockIdx.x*16;
  int nblk = blockIdx.y*128;
  int w  = tid>>6;             // wave 0..3 -> n-offset 32*w
  int ml = (tid&63)>>3;        // 8 m-lanes: rows 2*ml..2*ml+1
  int nl = tid&7;              // 8 n-lanes: cols 32*w+4*nl..+3
  int cc0 = 32*w + 4*nl;
  int row = r0 + 2*ml;

  const float* Wcol = W + cc0 + (size_t)((MODE==0 && nblk>=F) ? F*F : 0);
  float acc[2][4]={};

  auto seg = [&](const float* Ab0, int lda, int nk,
                 float m0, float m1,
                 const float* Wseg, int dm){
    int nt = nk/4;   // always multiple of 4 here (32 or 128)
    float4 Pa[2],Pb[4],Qa[2],Qb[4],Ra[2],Rc[4],Sa[2],Sb[4];
    RELOAD2(Pa,Pb,0);
    RELOAD2(Qa,Qb,1);
    RELOAD2(Ra,Rc,2);
    RELOAD2(Sa,Sb,3);
    for(int t=0;t<nt;t+=4){
      CONSUME2(Pa,Pb,t+4);
      CONSUME2(Qa,Qb,t+5);
      CONSUME2(Ra,Rc,t+6);
      CONSUME2(Sa,Sb,t+7);
    }
  };

  if(MODE==0){
    seg(A + (size_t)row*F, F, Ktot, 1.f,1.f, Wcol, 0);
  } else {
    float f10=F1p[row], f11=F1p[row+1];
    float f20=F2p[row], f21=F2p[row+1];
    const float* Ag = AGGp + (size_t)row*512;
    seg(CURp + (size_t)row*F, F, 128, 1.f,1.f, Wcol, 0);
    seg(Ag, 512, 512, 1.f,1.f, Wcol + (size_t)128*F, 0);
    seg(Ag, 512, 512, f10,f11, Wcol + (size_t)640*F, 1);
    seg(Ag, 512, 512, f20,f21, Wcol + (size_t)1152*F, 1);
  }

  #pragma unroll
  for(int i=0;i<2;i++){
    int rr = row + i;
    if(MODE==0){
      float4 o;
      if(nblk < F){
        o.x = acc[i][0]+bias[cc0  ]; o.y = acc[i][1]+bias[cc0+1];
        o.z = acc[i][2]+bias[cc0+2]; o.w = acc[i][3]+bias[cc0+3];
      } else {
        o.x = acc[i][0]; o.y = acc[i][1]; o.z = acc[i][2]; o.w = acc[i][3];
      }
      *(float4*)&out[(size_t)rr*256 + nblk + cc0] = o;
    } else {
      float4 o;
      o.x = acc[i][0]+bias[cc0  ]; o.y = acc[i][1]+bias[cc0+1];
      o.z = acc[i][2]+bias[cc0+2]; o.w = acc[i][3]+bias[cc0+3];
      *(float4*)&out[(size_t)rr*F + cc0] = o;
    }
  }
}

// fused tail: cur' = cur + H@Wlin + blin ; Z = (cur'@Wl + Rb + bl)*cur' ;
// ZZ = relu(Z@W1 + b1) ; score = ZZ@W2 + b2.  32 rows per block.
__global__ __launch_bounds__(256) void k_tail(
    const float* __restrict__ Hb, float* __restrict__ cur,
    const float* __restrict__ Wlin, const float* __restrict__ blin,
    const float* __restrict__ Wl, const float* __restrict__ bl,
    const float* __restrict__ W1, const float* __restrict__ b1,
    const float* __restrict__ W2, const float* __restrict__ b2,
    const float* __restrict__ RB, float* __restrict__ score)
{
  __shared__ float At [128][34];   // activations, transposed [c][r]
  __shared__ float At2[128][34];
  __shared__ float Bs [32][128];
  int tid = threadIdx.x;
  int r0 = blockIdx.x*32;
  int tm4 = (tid>>5)*4;
  int tn4 = (tid&31)*4;
  int am  = tid>>3;
  int ak4 = (tid&7)*4;
  int bk  = (tid>>5)*4;
  int bc  = (tid&31)*4;

  // stage At <- Hb rows (transposed)
  #pragma unroll
  for(int kb=0;kb<4;kb++){
    float4 v = *(const float4*)&Hb[(size_t)(r0+am)*F + kb*32 + ak4];
    At[kb*32+ak4  ][am] = v.x;
    At[kb*32+ak4+1][am] = v.y;
    At[kb*32+ak4+2][am] = v.z;
    At[kb*32+ak4+3][am] = v.w;
  }
  __syncthreads();

  float acc[4][4];

  // ---- Stage A: cur' = cur + At@Wlin + blin ----
  #pragma unroll
  for(int i=0;i<4;i++) for(int j=0;j<4;j++) acc[i][j]=0.f;
  for(int kt=0;kt<4;kt++){
    #pragma unroll
    for(int jj=0;jj<4;jj++)
      *(float4*)&Bs[bk+jj][bc] = *(const float4*)&Wlin[(size_t)(kt*32+bk+jj)*F + bc];
    __syncthreads();
    #pragma unroll
    for(int k=0;k<32;k++){
      float2 alo = *(const float2*)&At[kt*32+k][tm4];
      float2 ahi = *(const float2*)&At[kt*32+k][tm4+2];
      float4 bv  = *(const float4*)&Bs[k][tn4];
      float av[4] = {alo.x, alo.y, ahi.x, ahi.y};
      #pragma unroll
      for(int i=0;i<4;i++){
        acc[i][0]+=av[i]*bv.x; acc[i][1]+=av[i]*bv.y;
        acc[i][2]+=av[i]*bv.z; acc[i][3]+=av[i]*bv.w;
      }
    }
    __syncthreads();
  }
  #pragma unroll
  for(int i=0;i<4;i++){
    int rr = r0 + tm4 + i;
    float4 c4 = *(const float4*)&cur[(size_t)rr*F + tn4];
    float cv[4] = {c4.x, c4.y, c4.z, c4.w};
    float ov[4];
    #pragma unroll
    for(int j=0;j<4;j++){
      int cc = tn4 + j;
      float val = cv[j] + (acc[i][j] + blin[cc]);   // same order as MODE2
      ov[j] = val;
      At2[cc][tm4+i] = val;
    }
    float4 o4 = {ov[0],ov[1],ov[2],ov[3]};
    *(float4*)&cur[(size_t)rr*F + tn4] = o4;
  }
  __syncthreads();

  // ---- Stage B: Z = (At2@Wl + Rb + bl) * At2 ----
  #pragma unroll
  for(int i=0;i<4;i++) for(int j=0;j<4;j++) acc[i][j]=0.f;
  for(int kt=0;kt<4;kt++){
    #pragma unroll
    for(int jj=0;jj<4;jj++)
      *(float4*)&Bs[bk+jj][bc] = *(const float4*)&Wl[(size_t)(kt*32+bk+jj)*F + bc];
    __syncthreads();
    #pragma unroll
    for(int k=0;k<32;k++){
      float2 alo = *(const float2*)&At2[kt*32+k][tm4];
      float2 ahi = *(const float2*)&At2[kt*32+k][tm4+2];
      float4 bv  = *(const float4*)&Bs[k][tn4];
      float av[4] = {alo.x, alo.y, ahi.x, ahi.y};
      #pragma unroll
      for(int i=0;i<4;i++){
        acc[i][0]+=av[i]*bv.x; acc[i][1]+=av[i]*bv.y;
        acc[i][2]+=av[i]*bv.z; acc[i][3]+=av[i]*bv.w;
      }
    }
    __syncthreads();
  }
  #pragma unroll
  for(int i=0;i<4;i++){
    int rr = r0 + tm4 + i;
    int bidx = rr/NNODE;
    #pragma unroll
    for(int j=0;j<4;j++){
      int cc = tn4 + j;
      float h = acc[i][j] + bl[cc] + RB[bidx*F+cc];  // same order as MODE3
      float z = h * At2[cc][tm4+i];
      At[cc][tm4+i] = z;     // overwrite At (Hb dead)
    }
  }
  __syncthreads();

  // ---- Stage C: ZZ = relu(At@W1 + b1) ----
  #pragma unroll
  for(int i=0;i<4;i++) for(int j=0;j<4;j++) acc[i][j]=0.f;
  for(int kt=0;kt<4;kt++){
    #pragma unroll
    for(int jj=0;jj<4;jj++)
      *(float4*)&Bs[bk+jj][bc] = *(const float4*)&W1[(size_t)(kt*32+bk+jj)*F + bc];
    __syncthreads();
    #pragma unroll
    for(int k=0;k<32;k++){
      float2 alo = *(const float2*)&At[kt*32+k][tm4];
      float2 ahi = *(const float2*)&At[kt*32+k][tm4+2];
      float4 bv  = *(const float4*)&Bs[k][tn4];
      float av[4] = {alo.x, alo.y, ahi.x, ahi.y};
      #pragma unroll
      for(int i=0;i<4;i++){
        acc[i][0]+=av[i]*bv.x; acc[i][1]+=av[i]*bv.y;
        acc[i][2]+=av[i]*bv.z; acc[i][3]+=av[i]*bv.w;
      }
    }
    __syncthreads();
  }
  #pragma unroll
  for(int i=0;i<4;i++){
    #pragma unroll
    for(int j=0;j<4;j++){
      int cc = tn4 + j;
      float h = acc[i][j] + b1[cc];
      At2[cc][tm4+i] = h>0.f ? h : 0.f;
    }
  }
  __syncthreads();

  // ---- Stage D: score = ZZ@W2 + b2 (replicates k_w2 exactly) ----
  int wv = tid>>6, ln = tid&63;
  for(int r8=0;r8<8;r8++){
    int r = wv*8 + r8;
    float zx = At2[2*ln  ][r];
    float zy = At2[2*ln+1][r];
    float p = zx*W2[ln*2] + zy*W2[ln*2+1];
    for(int o=32;o;o>>=1) p += __shfl_down(p,o);
    if(ln==0) score[r0+r] = p + b2[0];
  }
}

// PNA aggregation: one wave per dest node, lane owns 2 features (edge-sequential sums)
__global__ void k_agg(const float* __restrict__ AB, const unsigned char* __restrict__ sel,
                      const int* __restrict__ csr_start, const int* __restrict__ csr_src,
                      float* __restrict__ AGGo, float* __restrict__ F1o, float* __restrict__ F2o){
  int node = blockIdx.x*4 + (threadIdx.x>>6);
  int lane = threadIdx.x&63;
  int b = node/NNODE;
  int nl = node - b*NNODE;
  int boff = b*NNODE;
  int e0=csr_start[nl], e1=csr_start[nl+1];
  int f0=lane*2;
  float2 c = *(const float2*)&AB[(size_t)node*256 + f0]; // Acol + bpre
  float s1x=0,s1y=0,s2x=0,s2y=0;
  float mxx=-3e38f,mxy=-3e38f,mnx=3e38f,mny=3e38f;
  int cnt=0;
  for(int base=e0;base<e1;base+=64){
    int nch = e1-base; if(nch>64) nch=64;
    int pack=-1;
    if(lane<nch){
      int sg = csr_src[base+lane]+boff;
      pack = sel[sg] ? sg : -1;
    }
    for(int t=0;t<nch;t++){
      int sg = __shfl(pack, t);
      if(sg>=0){
        float2 v = *(const float2*)&AB[(size_t)sg*256 + F + f0]; // Brow[src]
        float ma = c.x+v.x, mb = c.y+v.y;
        s1x+=ma; s1y+=mb;
        s2x+=ma*ma; s2y+=mb*mb;
        mxx=fmaxf(mxx,ma); mxy=fmaxf(mxy,mb);
        mnx=fminf(mnx,ma); mny=fminf(mny,mb);
        cnt++;
      }
    }
  }
  float meanx,meany,stdx,stdy,mxox,mxoy,mnox,mnoy;
  if(cnt>0){
    float fc=(float)cnt;
    meanx=s1x/fc; meany=s1y/fc;
    float m2x=s2x/fc, m2y=s2y/fc;
    float vx=m2x-meanx*meanx; if(vx<0.f)vx=0.f;
    float vy=m2y-meany*meany; if(vy<0.f)vy=0.f;
    stdx=sqrtf(vx+EPSSTD); stdy=sqrtf(vy+EPSSTD);
    mxox=mxx; mxoy=mxy; mnox=mnx; mnoy=mny;
  } else {
    meanx=0.f; meany=0.f;
    stdx=sqrtf(EPSSTD); stdy=stdx;
    mxox=0.f; mxoy=0.f; mnox=0.f; mnoy=0.f;
  }
  float logd = logf(fmaxf((float)cnt,1.f)+1.f);
  float2 w0={meanx,meany}; *(float2*)&AGGo[(size_t)node*512      +f0]=w0;
  float2 w1={mxox,mxoy};   *(float2*)&AGGo[(size_t)node*512+F    +f0]=w1;
  float2 w2v={mnox,mnoy};  *(float2*)&AGGo[(size_t)node*512+2*F  +f0]=w2v;
  float2 w3={stdx,stdy};   *(float2*)&AGGo[(size_t)node*512+3*F  +f0]=w3;
  if(lane==0){ F1o[node]=logd/AVGLOG; F2o[node]=AVGLOG/logd; }
}

__global__ void k_gather(const float* __restrict__ score, const int* __restrict__ meta_i,
                         float* __restrict__ outp){
  int t = threadIdx.x;
  if(t<128) outp[t] = score[meta_i[16+t]];
}

// ---------------- launch ----------------

extern "C" void kernel_launch(void* const* d_in, const int* in_sizes, int n_in,
                              void* d_out, int out_size, void* d_ws, size_t ws_size,
                              hipStream_t stream){
  const int*   h_index    = (const int*)d_in[0];
  const int*   r_index    = (const int*)d_in[1];
  const int*   t_index    = (const int*)d_in[2];
  const float* hidden     = (const float*)d_in[3];
  const float* rel_hidden = (const float*)d_in[4];
  const int*   edge       = (const int*)d_in[5];
  const float* rel_table  = (const float*)d_in[8];
  const float* Wl =(const float*)d_in[9];   const float* bl =(const float*)d_in[10];
  const float* W1 =(const float*)d_in[11];  const float* b1 =(const float*)d_in[12];
  const float* W2 =(const float*)d_in[13];  const float* b2 =(const float*)d_in[14];
  const float* Wpre =(const float*)d_in[15];  const float* bpre =(const float*)d_in[16];
  const float* Wpost=(const float*)d_in[17];  const float* bpost=(const float*)d_in[18];
  const float* Wlin =(const float*)d_in[19];  const float* blin =(const float*)d_in[20];

  char* ws=(char*)d_ws;
  size_t off=0;
  auto alloc=[&](size_t bytes)->char*{ char* p=ws+off; off=(off+bytes+255)&~(size_t)255; return p; };
  float* cur   =(float*)alloc((size_t)NN*F*4);
  float* AB    =(float*)alloc((size_t)NN*256*4);
  float* AGG   =(float*)alloc((size_t)NN*512*4);
  float* Hb    =(float*)alloc((size_t)NN*F*4);
  float* score =(float*)alloc((size_t)NN*4);
  float* F1b   =(float*)alloc((size_t)NN*4);
  float* F2b   =(float*)alloc((size_t)NN*4);
  float* meta_f=(float*)alloc(2048*4);
  int*   meta_i=(int*)alloc(256*4);
  int*   deg   =(int*)alloc(NNODE*4);
  int*   csr_start=(int*)alloc((NNODE+1)*4);
  int*   csr_src  =(int*)alloc((size_t)NEDGE*4);
  int*   hist  =(int*)alloc((size_t)NCHUNK*NNODE*4);
  int*   rank  =(int*)alloc((size_t)NEDGE*4);
  unsigned char* sel=(unsigned char*)alloc(NN);

  k_init<<<512,256,0,stream>>>(cur, hist);
  k_meta<<<1,256,0,stream>>>(h_index,r_index,t_index,hidden,rel_hidden,rel_table,
                             Wl,bl,W1,b1,W2,b2,cur,sel,meta_i,meta_f);
  k_hist<<<NCHUNK,256,0,stream>>>(edge, hist, rank);
  k_chunkscan<<<8,256,0,stream>>>(hist, deg);
  k_scan<<<1,256,0,stream>>>(deg, csr_start);
  k_scatter<<<250,256,0,stream>>>(edge, hist, rank, csr_start, csr_src);

  for(int l=0;l<3;l++){
    if(l) k_sel<<<250,256,0,stream>>>(score, sel);
    k_gemm<0><<<dim3(500,2),256,0,stream>>>(cur, Wpre+(size_t)l*256*F, bpre+l*F, AB,
                                            nullptr,nullptr,nullptr,nullptr, F);
    k_agg<<<2000,256,0,stream>>>(AB, sel, csr_start, csr_src, AGG, F1b, F2b);
    k_gemm<1><<<dim3(500,1),256,0,stream>>>(nullptr, Wpost+(size_t)l*1664*F, bpost+l*F, Hb,
                                            AGG, F1b, F2b, cur, 1664);
    k_tail<<<250,256,0,stream>>>(Hb, cur, Wlin+(size_t)l*F*F, blin+l*F,
                                 Wl, bl, W1, b1, W2, b2, meta_f+512, score);
  }
  k_gather<<<1,128,0,stream>>>(score, meta_i, (float*)d_out);
}

// Round 9
// 648.619 us; speedup vs baseline: 1.3219x; 1.3219x over previous
//
#include <hip/hip_runtime.h>

#define F 128
#define NNODE 2000
#define NEDGE 64000
#define NBATCH 4
#define NN 8000          // NBATCH*NNODE
#define NRELC 18
#define KTOP 800         // int(0.1*8000)
#define AVGLOG 3.4965075614664802f   // float(np.log(33.0))
#define EPSSTD 1e-5f
#define NCHUNK 250       // NEDGE/256

// ---------------- setup kernels ----------------

__global__ void k_init(float* __restrict__ cur, int* __restrict__ hist){
  int i = blockIdx.x*blockDim.x + threadIdx.x;
  int stride = gridDim.x*blockDim.x;
  for(int t=i;t<NN*F;t+=stride) cur[t]=0.f;
  for(int t=i;t<NCHUNK*NNODE;t+=stride) hist[t]=0;
}

// single block: indices, rel_emb, Rb = rel@Wl[128:], initial scores, sel0, xr scatter
__global__ void k_meta(const int* __restrict__ h_index, const int* __restrict__ r_index,
                       const int* __restrict__ t_index, const float* __restrict__ hidden,
                       const float* __restrict__ rel_hidden, const float* __restrict__ rel_table,
                       const float* __restrict__ Wl, const float* __restrict__ bl,
                       const float* __restrict__ W1, const float* __restrict__ b1,
                       const float* __restrict__ W2, const float* __restrict__ b2,
                       float* __restrict__ cur, unsigned char* __restrict__ sel,
                       int* __restrict__ meta_i, float* __restrict__ meta_f){
  __shared__ int sh_ist[NBATCH], sh_h0[NBATCH], sh_t0[NBATCH], sh_r0[NBATCH];
  __shared__ float sh_rel[NBATCH*F];
  __shared__ float sh_z[F], sh_zz[F];
  __shared__ float sh_sc[NBATCH];
  __shared__ int sh_excl;
  int tid = threadIdx.x;
  if(tid<NBATCH){
    int b=tid;
    int h00=h_index[b*32];
    int ist=1;
    for(int j=1;j<32;j++) if(h_index[b*32+j]!=h00) ist=0;
    sh_ist[b]=ist;
    sh_h0[b] = (ist ? h_index[b*32] : t_index[b*32]) + b*NNODE;
    sh_t0[b] = (ist ? t_index[b*32] : h_index[b*32]) + b*NNODE;
    sh_r0[b] = r_index[b*32] + (ist?0:NRELC);
  }
  __syncthreads();
  if(tid<NBATCH*32){
    int b=tid>>5;
    meta_i[16+tid] = (sh_ist[b] ? t_index[tid] : h_index[tid]) + b*NNODE; // final gather idx
  }
  for(int t=tid;t<NBATCH*F;t+=blockDim.x){
    int b=t>>7, f=t&127;
    float v = rel_table[sh_r0[b]*F+f];
    sh_rel[t]=v; meta_f[t]=v;
  }
  __syncthreads();
  // Rb[b][f] = sum_k rel[b][k]*Wl[128+k][f]
  for(int t=tid;t<NBATCH*F;t+=blockDim.x){
    int b=t>>7, f=t&127;
    float acc=0.f;
    for(int k=0;k<F;k++) acc += sh_rel[b*F+k]*Wl[(F+k)*F+f];
    meta_f[512+t]=acc;
  }
  __syncthreads();
  // initial scores sc[b] = _score(hidden_b, rel_b)
  for(int b=0;b<NBATCH;b++){
    if(tid<F){
      float acc=0.f;
      for(int k=0;k<F;k++) acc += hidden[b*F+k]*Wl[k*F+tid];
      float heur = acc + meta_f[512+b*F+tid] + bl[tid];
      sh_z[tid] = heur*hidden[b*F+tid];
    }
    __syncthreads();
    if(tid<F){
      float acc=0.f;
      for(int k=0;k<F;k++) acc += sh_z[k]*W1[k*F+tid];
      acc += b1[tid];
      sh_zz[tid] = acc>0.f?acc:0.f;
    }
    __syncthreads();
    if(tid==0){
      float s=0.f;
      for(int k=0;k<F;k++) s += sh_zz[k]*W2[k];
      sh_sc[b] = s + b2[0];
      meta_f[1024+b]=sh_sc[b];
    }
    __syncthreads();
  }
  if(tid==0){
    // layer-0 top_k over repeat(s0,N): only first-8000 entries matter; all zero-ties
    // get selected. Exclusion only if batch0's h0 node < 4 AND its score negative.
    sh_excl = (sh_h0[0]<4 && sh_sc[0]<0.f) ? sh_h0[0] : -1;
    meta_i[8]=sh_excl;
  }
  __syncthreads();
  int ex = sh_excl;
  for(int t=tid;t<NN;t+=blockDim.x)
    sel[t] = (ex>=0 && (t/NNODE)==ex) ? 0 : 1;
  // xr scatter: t rows first, then h rows (h wins collisions)
  for(int t=tid;t<NBATCH*F;t+=blockDim.x){
    int b=t>>7, f=t&127;
    cur[sh_t0[b]*F+f] = rel_hidden[t];
  }
  __syncthreads();
  for(int t=tid;t<NBATCH*F;t+=blockDim.x){
    int b=t>>7, f=t&127;
    cur[sh_h0[b]*F+f] = hidden[t];
  }
}

// stable counting-sort CSR build, O(E)
__global__ __launch_bounds__(256) void k_hist(const int* __restrict__ edge,
                                              int* __restrict__ hist, int* __restrict__ rank){
  __shared__ int dsts[256];
  int chunk = blockIdx.x;
  int tid = threadIdx.x;
  int e = chunk*256 + tid;
  int d = edge[NEDGE + e];
  dsts[tid] = d;
  __syncthreads();
  int before=0, after=0;
  #pragma unroll 8
  for(int t=0;t<256;t++){
    int dt = dsts[t];
    before += (dt==d) & (t<tid);
    after  += (dt==d) & (t>tid);
  }
  rank[e] = before;
  if(after==0) hist[chunk*NNODE + d] = before+1;
}

__global__ void k_chunkscan(int* __restrict__ hist, int* __restrict__ deg){
  int node = blockIdx.x*blockDim.x + threadIdx.x;
  if(node>=NNODE) return;
  int run=0;
  for(int c=0;c<NCHUNK;c++){
    int v = hist[c*NNODE+node];
    hist[c*NNODE+node] = run;
    run += v;
  }
  deg[node]=run;
}

__global__ void k_scan(const int* __restrict__ deg, int* __restrict__ csr_start){
  __shared__ int a[2048], b[2048];
  int tid=threadIdx.x;
  for(int i=tid;i<2048;i+=256) a[i] = (i<NNODE)? deg[i] : 0;
  __syncthreads();
  int* src=a; int* dst=b;
  for(int off=1; off<2048; off<<=1){
    for(int i=tid;i<2048;i+=256){
      int v = src[i];
      if(i>=off) v += src[i-off];
      dst[i]=v;
    }
    __syncthreads();
    int* t=src; src=dst; dst=t;
  }
  for(int i=tid;i<=NNODE;i+=256) csr_start[i] = (i==0)?0:src[i-1];
}

__global__ void k_scatter(const int* __restrict__ edge, const int* __restrict__ hist,
                          const int* __restrict__ rank, const int* __restrict__ csr_start,
                          int* __restrict__ csr_src){
  int e = blockIdx.x*blockDim.x + threadIdx.x;
  if(e<NEDGE){
    int d = edge[NEDGE+e];
    int pos = csr_start[d] + hist[(e>>8)*NNODE + d] + rank[e];
    csr_src[pos] = edge[e];
  }
}

// ---------------- per-layer kernels ----------------

// exact top-800-of-8000 with lax.top_k tie semantics (lower index wins ties)
__global__ void k_sel(const float* __restrict__ score, unsigned char* __restrict__ sel){
  __shared__ float s[NN];
  int tid=threadIdx.x;
  float4* s4 = (float4*)s;
  const float4* g4 = (const float4*)score;
  for(int i=tid;i<NN/4;i+=256) s4[i]=g4[i];
  __syncthreads();
  int node = blockIdx.x*32 + (tid>>3);
  int part = tid & 7;
  float si = s[node];
  int rank = 0;
  for(int q=part*(NN/32); q<(part+1)*(NN/32); q++){
    float4 v = s4[q];
    int j = q*4;
    rank += (v.x>si)||(v.x==si && j  <node);
    rank += (v.y>si)||(v.y==si && j+1<node);
    rank += (v.z>si)||(v.z==si && j+2<node);
    rank += (v.w>si)||(v.w==si && j+3<node);
  }
  for(int o=4;o;o>>=1) rank += __shfl_down(rank, o, 8);
  if(part==0) sel[node] = (rank < KTOP) ? 1 : 0;
}

// fp32 GEMM (R2-proven config): BM=64 x BN=32, BK=32, 256 thr, thread-tile 2x4,
// single-buffered LDS, pad 36. Per-output-element k-sequential FMA chain.
// MODE 0: AB = cur @ [Wpre_dst|Wpre_src] (+bpre on first 128 cols), out ld 256
// MODE 1: H  = [cur|AGG|AGG*f1|AGG*f2] @ Wpost + bpost   (virtual A)
#define BM 64
#define BN 32
#define BKK 32
template<int MODE>
__global__ __launch_bounds__(256) void k_gemm(
    const float* __restrict__ A, const float* __restrict__ W,
    const float* __restrict__ bias, float* __restrict__ out,
    const float* __restrict__ AGGp, const float* __restrict__ F1p,
    const float* __restrict__ F2p, const float* __restrict__ CURp, int Ktot)
{
  __shared__ float As[BM][36];
  __shared__ float Bs[BKK][36];
  int tid=threadIdx.x;
  int r0 = blockIdx.x*BM;
  int nblk = blockIdx.y*BN;
  int m0 = (tid>>3)*2;
  int n0 = (tid&7)*4;
  int am = tid>>2, ak=(tid&3)*8;
  int brw = tid>>3, bc=(tid&7)*4;
  float acc[2][4]={};
  for(int k0=0;k0<Ktot;k0+=BKK){
    {
      int row=r0+am;
      const float* src; float mult=1.f;
      if(MODE==1){
        if(k0<F)         src = CURp + (size_t)row*F   + k0;
        else if(k0<640)  src = AGGp + (size_t)row*512 + (k0-F);
        else if(k0<1152){ src = AGGp + (size_t)row*512 + (k0-640);  mult=F1p[row]; }
        else            { src = AGGp + (size_t)row*512 + (k0-1152); mult=F2p[row]; }
      } else src = A + (size_t)row*F + k0;
      float4 v0 = *(const float4*)(src+ak);
      float4 v1 = *(const float4*)(src+ak+4);
      if(MODE==1){
        v0.x*=mult; v0.y*=mult; v0.z*=mult; v0.w*=mult;
        v1.x*=mult; v1.y*=mult; v1.z*=mult; v1.w*=mult;
      }
      *(float4*)&As[am][ak]   = v0;
      *(float4*)&As[am][ak+4] = v1;
    }
    {
      int wr=k0+brw, wc=nblk+bc;
      if(MODE==0 && nblk>=F){ wr+=F; wc-=F; } // second weight half for Brow columns
      *(float4*)&Bs[brw][bc] = *(const float4*)&W[(size_t)wr*F+wc];
    }
    __syncthreads();
    #pragma unroll
    for(int k=0;k<BKK;k++){
      float a0=As[m0][k], a1=As[m0+1][k];
      float4 b=*(float4*)&Bs[k][n0];
      acc[0][0]+=a0*b.x; acc[0][1]+=a0*b.y; acc[0][2]+=a0*b.z; acc[0][3]+=a0*b.w;
      acc[1][0]+=a1*b.x; acc[1][1]+=a1*b.y; acc[1][2]+=a1*b.z; acc[1][3]+=a1*b.w;
    }
    __syncthreads();
  }
  #pragma unroll
  for(int i=0;i<2;i++){
    int rr=r0+m0+i;
    #pragma unroll
    for(int j=0;j<4;j++){
      int cc=nblk+n0+j;
      float v=acc[i][j];
      if(MODE==0){ if(cc<F) v+=bias[cc]; out[(size_t)rr*256+cc]=v; }
      else       { out[(size_t)rr*F+cc]=v+bias[cc]; }
    }
  }
}

// fused tail: cur' = cur + H@Wlin + blin ; Z = (cur'@Wl + Rb + bl)*cur' ;
// ZZ = relu(Z@W1 + b1) ; score = ZZ@W2 + b2.  32 rows per block.
__global__ __launch_bounds__(256) void k_tail(
    const float* __restrict__ Hb, float* __restrict__ cur,
    const float* __restrict__ Wlin, const float* __restrict__ blin,
    const float* __restrict__ Wl, const float* __restrict__ bl,
    const float* __restrict__ W1, const float* __restrict__ b1,
    const float* __restrict__ W2, const float* __restrict__ b2,
    const float* __restrict__ RB, float* __restrict__ score)
{
  __shared__ float At [128][34];   // activations, transposed [c][r]
  __shared__ float At2[128][34];
  __shared__ float Bs [32][128];
  int tid = threadIdx.x;
  int r0 = blockIdx.x*32;
  int tm4 = (tid>>5)*4;
  int tn4 = (tid&31)*4;
  int am  = tid>>3;
  int ak4 = (tid&7)*4;
  int bk  = (tid>>5)*4;
  int bc  = (tid&31)*4;

  // stage At <- Hb rows (transposed)
  #pragma unroll
  for(int kb=0;kb<4;kb++){
    float4 v = *(const float4*)&Hb[(size_t)(r0+am)*F + kb*32 + ak4];
    At[kb*32+ak4  ][am] = v.x;
    At[kb*32+ak4+1][am] = v.y;
    At[kb*32+ak4+2][am] = v.z;
    At[kb*32+ak4+3][am] = v.w;
  }
  __syncthreads();

  float acc[4][4];

  // ---- Stage A: cur' = cur + At@Wlin + blin ----
  #pragma unroll
  for(int i=0;i<4;i++) for(int j=0;j<4;j++) acc[i][j]=0.f;
  for(int kt=0;kt<4;kt++){
    #pragma unroll
    for(int jj=0;jj<4;jj++)
      *(float4*)&Bs[bk+jj][bc] = *(const float4*)&Wlin[(size_t)(kt*32+bk+jj)*F + bc];
    __syncthreads();
    #pragma unroll
    for(int k=0;k<32;k++){
      float2 alo = *(const float2*)&At[kt*32+k][tm4];
      float2 ahi = *(const float2*)&At[kt*32+k][tm4+2];
      float4 bv  = *(const float4*)&Bs[k][tn4];
      float av[4] = {alo.x, alo.y, ahi.x, ahi.y};
      #pragma unroll
      for(int i=0;i<4;i++){
        acc[i][0]+=av[i]*bv.x; acc[i][1]+=av[i]*bv.y;
        acc[i][2]+=av[i]*bv.z; acc[i][3]+=av[i]*bv.w;
      }
    }
    __syncthreads();
  }
  #pragma unroll
  for(int i=0;i<4;i++){
    int rr = r0 + tm4 + i;
    float4 c4 = *(const float4*)&cur[(size_t)rr*F + tn4];
    float cv[4] = {c4.x, c4.y, c4.z, c4.w};
    float ov[4];
    #pragma unroll
    for(int j=0;j<4;j++){
      int cc = tn4 + j;
      float val = cv[j] + (acc[i][j] + blin[cc]);   // same order as MODE2
      ov[j] = val;
      At2[cc][tm4+i] = val;
    }
    float4 o4 = {ov[0],ov[1],ov[2],ov[3]};
    *(float4*)&cur[(size_t)rr*F + tn4] = o4;
  }
  __syncthreads();

  // ---- Stage B: Z = (At2@Wl + Rb + bl) * At2 ----
  #pragma unroll
  for(int i=0;i<4;i++) for(int j=0;j<4;j++) acc[i][j]=0.f;
  for(int kt=0;kt<4;kt++){
    #pragma unroll
    for(int jj=0;jj<4;jj++)
      *(float4*)&Bs[bk+jj][bc] = *(const float4*)&Wl[(size_t)(kt*32+bk+jj)*F + bc];
    __syncthreads();
    #pragma unroll
    for(int k=0;k<32;k++){
      float2 alo = *(const float2*)&At2[kt*32+k][tm4];
      float2 ahi = *(const float2*)&At2[kt*32+k][tm4+2];
      float4 bv  = *(const float4*)&Bs[k][tn4];
      float av[4] = {alo.x, alo.y, ahi.x, ahi.y};
      #pragma unroll
      for(int i=0;i<4;i++){
        acc[i][0]+=av[i]*bv.x; acc[i][1]+=av[i]*bv.y;
        acc[i][2]+=av[i]*bv.z; acc[i][3]+=av[i]*bv.w;
      }
    }
    __syncthreads();
  }
  #pragma unroll
  for(int i=0;i<4;i++){
    int rr = r0 + tm4 + i;
    int bidx = rr/NNODE;
    #pragma unroll
    for(int j=0;j<4;j++){
      int cc = tn4 + j;
      float h = acc[i][j] + bl[cc] + RB[bidx*F+cc];  // same order as MODE3
      float z = h * At2[cc][tm4+i];
      At[cc][tm4+i] = z;     // overwrite At (Hb dead)
    }
  }
  __syncthreads();

  // ---- Stage C: ZZ = relu(At@W1 + b1) ----
  #pragma unroll
  for(int i=0;i<4;i++) for(int j=0;j<4;j++) acc[i][j]=0.f;
  for(int kt=0;kt<4;kt++){
    #pragma unroll
    for(int jj=0;jj<4;jj++)
      *(float4*)&Bs[bk+jj][bc] = *(const float4*)&W1[(size_t)(kt*32+bk+jj)*F + bc];
    __syncthreads();
    #pragma unroll
    for(int k=0;k<32;k++){
      float2 alo = *(const float2*)&At[kt*32+k][tm4];
      float2 ahi = *(const float2*)&At[kt*32+k][tm4+2];
      float4 bv  = *(const float4*)&Bs[k][tn4];
      float av[4] = {alo.x, alo.y, ahi.x, ahi.y};
      #pragma unroll
      for(int i=0;i<4;i++){
        acc[i][0]+=av[i]*bv.x; acc[i][1]+=av[i]*bv.y;
        acc[i][2]+=av[i]*bv.z; acc[i][3]+=av[i]*bv.w;
      }
    }
    __syncthreads();
  }
  #pragma unroll
  for(int i=0;i<4;i++){
    #pragma unroll
    for(int j=0;j<4;j++){
      int cc = tn4 + j;
      float h = acc[i][j] + b1[cc];
      At2[cc][tm4+i] = h>0.f ? h : 0.f;
    }
  }
  __syncthreads();

  // ---- Stage D: score = ZZ@W2 + b2 (replicates k_w2 exactly) ----
  int wv = tid>>6, ln = tid&63;
  for(int r8=0;r8<8;r8++){
    int r = wv*8 + r8;
    float zx = At2[2*ln  ][r];
    float zy = At2[2*ln+1][r];
    float p = zx*W2[ln*2] + zy*W2[ln*2+1];
    for(int o=32;o;o>>=1) p += __shfl_down(p,o);
    if(ln==0) score[r0+r] = p + b2[0];
  }
}

// PNA aggregation: one wave per dest node, lane owns 2 features.
// Edge loads batched 4-wide (independent loads pipelined); accumulation stays
// strictly in edge order (bitwise-identical summation chain).
__global__ void k_agg(const float* __restrict__ AB, const unsigned char* __restrict__ sel,
                      const int* __restrict__ csr_start, const int* __restrict__ csr_src,
                      float* __restrict__ AGGo, float* __restrict__ F1o, float* __restrict__ F2o){
  int node = blockIdx.x*4 + (threadIdx.x>>6);
  int lane = threadIdx.x&63;
  int b = node/NNODE;
  int nl = node - b*NNODE;
  int boff = b*NNODE;
  int e0=csr_start[nl], e1=csr_start[nl+1];
  int f0=lane*2;
  float2 c = *(const float2*)&AB[(size_t)node*256 + f0]; // Acol + bpre
  float s1x=0,s1y=0,s2x=0,s2y=0;
  float mxx=-3e38f,mxy=-3e38f,mnx=3e38f,mny=3e38f;
  int cnt=0;
  for(int base=e0;base<e1;base+=64){
    int nch = e1-base; if(nch>64) nch=64;
    int pack=-1;
    if(lane<nch){
      int sg = csr_src[base+lane]+boff;
      pack = sel[sg] ? sg : -1;
    }
    int t=0;
    for(; t+4<=nch; t+=4){
      int sg0 = __shfl(pack, t  );
      int sg1 = __shfl(pack, t+1);
      int sg2 = __shfl(pack, t+2);
      int sg3 = __shfl(pack, t+3);
      // issue all valid loads first (independent), then accumulate in edge order
      float2 v0,v1,v2,v3;
      if(sg0>=0) v0 = *(const float2*)&AB[(size_t)sg0*256 + F + f0];
      if(sg1>=0) v1 = *(const float2*)&AB[(size_t)sg1*256 + F + f0];
      if(sg2>=0) v2 = *(const float2*)&AB[(size_t)sg2*256 + F + f0];
      if(sg3>=0) v3 = *(const float2*)&AB[(size_t)sg3*256 + F + f0];
      if(sg0>=0){ float ma=c.x+v0.x, mb=c.y+v0.y;
        s1x+=ma; s1y+=mb; s2x+=ma*ma; s2y+=mb*mb;
        mxx=fmaxf(mxx,ma); mxy=fmaxf(mxy,mb); mnx=fminf(mnx,ma); mny=fminf(mny,mb); cnt++; }
      if(sg1>=0){ float ma=c.x+v1.x, mb=c.y+v1.y;
        s1x+=ma; s1y+=mb; s2x+=ma*ma; s2y+=mb*mb;
        mxx=fmaxf(mxx,ma); mxy=fmaxf(mxy,mb); mnx=fminf(mnx,ma); mny=fminf(mny,mb); cnt++; }
      if(sg2>=0){ float ma=c.x+v2.x, mb=c.y+v2.y;
        s1x+=ma; s1y+=mb; s2x+=ma*ma; s2y+=mb*mb;
        mxx=fmaxf(mxx,ma); mxy=fmaxf(mxy,mb); mnx=fminf(mnx,ma); mny=fminf(mny,mb); cnt++; }
      if(sg3>=0){ float ma=c.x+v3.x, mb=c.y+v3.y;
        s1x+=ma; s1y+=mb; s2x+=ma*ma; s2y+=mb*mb;
        mxx=fmaxf(mxx,ma); mxy=fmaxf(mxy,mb); mnx=fminf(mnx,ma); mny=fminf(mny,mb); cnt++; }
    }
    for(; t<nch; t++){
      int sg = __shfl(pack, t);
      if(sg>=0){
        float2 v = *(const float2*)&AB[(size_t)sg*256 + F + f0];
        float ma = c.x+v.x, mb = c.y+v.y;
        s1x+=ma; s1y+=mb;
        s2x+=ma*ma; s2y+=mb*mb;
        mxx=fmaxf(mxx,ma); mxy=fmaxf(mxy,mb);
        mnx=fminf(mnx,ma); mny=fminf(mny,mb);
        cnt++;
      }
    }
  }
  float meanx,meany,stdx,stdy,mxox,mxoy,mnox,mnoy;
  if(cnt>0){
    float fc=(float)cnt;
    meanx=s1x/fc; meany=s1y/fc;
    float m2x=s2x/fc, m2y=s2y/fc;
    float vx=m2x-meanx*meanx; if(vx<0.f)vx=0.f;
    float vy=m2y-meany*meany; if(vy<0.f)vy=0.f;
    stdx=sqrtf(vx+EPSSTD); stdy=sqrtf(vy+EPSSTD);
    mxox=mxx; mxoy=mxy; mnox=mnx; mnoy=mny;
  } else {
    meanx=0.f; meany=0.f;
    stdx=sqrtf(EPSSTD); stdy=stdx;
    mxox=0.f; mxoy=0.f; mnox=0.f; mnoy=0.f;
  }
  float logd = logf(fmaxf((float)cnt,1.f)+1.f);
  float2 w0={meanx,meany}; *(float2*)&AGGo[(size_t)node*512      +f0]=w0;
  float2 w1={mxox,mxoy};   *(float2*)&AGGo[(size_t)node*512+F    +f0]=w1;
  float2 w2v={mnox,mnoy};  *(float2*)&AGGo[(size_t)node*512+2*F  +f0]=w2v;
  float2 w3={stdx,stdy};   *(float2*)&AGGo[(size_t)node*512+3*F  +f0]=w3;
  if(lane==0){ F1o[node]=logd/AVGLOG; F2o[node]=AVGLOG/logd; }
}

__global__ void k_gather(const float* __restrict__ score, const int* __restrict__ meta_i,
                         float* __restrict__ outp){
  int t = threadIdx.x;
  if(t<128) outp[t] = score[meta_i[16+t]];
}

// ---------------- launch ----------------

extern "C" void kernel_launch(void* const* d_in, const int* in_sizes, int n_in,
                              void* d_out, int out_size, void* d_ws, size_t ws_size,
                              hipStream_t stream){
  const int*   h_index    = (const int*)d_in[0];
  const int*   r_index    = (const int*)d_in[1];
  const int*   t_index    = (const int*)d_in[2];
  const float* hidden     = (const float*)d_in[3];
  const float* rel_hidden = (const float*)d_in[4];
  const int*   edge       = (const int*)d_in[5];
  const float* rel_table  = (const float*)d_in[8];
  const float* Wl =(const float*)d_in[9];   const float* bl =(const float*)d_in[10];
  const float* W1 =(const float*)d_in[11];  const float* b1 =(const float*)d_in[12];
  const float* W2 =(const float*)d_in[13];  const float* b2 =(const float*)d_in[14];
  const float* Wpre =(const float*)d_in[15];  const float* bpre =(const float*)d_in[16];
  const float* Wpost=(const float*)d_in[17];  const float* bpost=(const float*)d_in[18];
  const float* Wlin =(const float*)d_in[19];  const float* blin =(const float*)d_in[20];

  char* ws=(char*)d_ws;
  size_t off=0;
  auto alloc=[&](size_t bytes)->char*{ char* p=ws+off; off=(off+bytes+255)&~(size_t)255; return p; };
  float* cur   =(float*)alloc((size_t)NN*F*4);
  float* AB    =(float*)alloc((size_t)NN*256*4);
  float* AGG   =(float*)alloc((size_t)NN*512*4);
  float* Hb    =(float*)alloc((size_t)NN*F*4);
  float* score =(float*)alloc((size_t)NN*4);
  float* F1b   =(float*)alloc((size_t)NN*4);
  float* F2b   =(float*)alloc((size_t)NN*4);
  float* meta_f=(float*)alloc(2048*4);
  int*   meta_i=(int*)alloc(256*4);
  int*   deg   =(int*)alloc(NNODE*4);
  int*   csr_start=(int*)alloc((NNODE+1)*4);
  int*   csr_src  =(int*)alloc((size_t)NEDGE*4);
  int*   hist  =(int*)alloc((size_t)NCHUNK*NNODE*4);
  int*   rank  =(int*)alloc((size_t)NEDGE*4);
  unsigned char* sel=(unsigned char*)alloc(NN);

  k_init<<<512,256,0,stream>>>(cur, hist);
  k_meta<<<1,256,0,stream>>>(h_index,r_index,t_index,hidden,rel_hidden,rel_table,
                             Wl,bl,W1,b1,W2,b2,cur,sel,meta_i,meta_f);
  k_hist<<<NCHUNK,256,0,stream>>>(edge, hist, rank);
  k_chunkscan<<<8,256,0,stream>>>(hist, deg);
  k_scan<<<1,256,0,stream>>>(deg, csr_start);
  k_scatter<<<250,256,0,stream>>>(edge, hist, rank, csr_start, csr_src);

  for(int l=0;l<3;l++){
    if(l) k_sel<<<250,256,0,stream>>>(score, sel);
    k_gemm<0><<<dim3(125,8),256,0,stream>>>(cur, Wpre+(size_t)l*256*F, bpre+l*F, AB,
                                            nullptr,nullptr,nullptr,nullptr, F);
    k_agg<<<2000,256,0,stream>>>(AB, sel, csr_start, csr_src, AGG, F1b, F2b);
    k_gemm<1><<<dim3(125,4),256,0,stream>>>(nullptr, Wpost+(size_t)l*1664*F, bpost+l*F, Hb,
                                            AGG, F1b, F2b, cur, 1664);
    k_tail<<<250,256,0,stream>>>(Hb, cur, Wlin+(size_t)l*F*F, blin+l*F,
                                 Wl, bl, W1, b1, W2, b2, meta_f+512, score);
  }
  k_gather<<<1,128,0,stream>>>(score, meta_i, (float*)d_out);
}